// Round 1
// baseline (149.957 us; speedup 1.0000x reference)
//
#include <hip/hip_runtime.h>

#define N_RAYS 262144
#define N_SAMPLES 128

// One wave (64 lanes) per ray; 2 consecutive samples per lane.
// Exclusive cumprod of (1 - alpha + 1e-10) via wave prefix-product scan.
__global__ __launch_bounds__(256) void volrend_kernel(
    const float* __restrict__ sigma,
    const float* __restrict__ colors,
    const float* __restrict__ z_vals,
    const float* __restrict__ rays_d,
    float* __restrict__ out)
{
    const int lane = threadIdx.x & 63;
    const int ray  = blockIdx.x * 4 + (threadIdx.x >> 6);

    // ---- loads (coalesced float2 across the wave) ----
    const float dx = rays_d[ray * 3 + 0];
    const float dy = rays_d[ray * 3 + 1];
    const float dz = rays_d[ray * 3 + 2];
    const float nrm = sqrtf(dx * dx + dy * dy + dz * dz);

    const int s0 = lane * 2;
    const size_t rbase = (size_t)ray * N_SAMPLES;
    const float2 zv = *reinterpret_cast<const float2*>(z_vals + rbase + s0);
    const float2 sg = *reinterpret_cast<const float2*>(sigma  + rbase + s0);
    const float* cbase = colors + rbase * 3 + (size_t)s0 * 3;
    const float2 c01 = *reinterpret_cast<const float2*>(cbase + 0);
    const float2 c23 = *reinterpret_cast<const float2*>(cbase + 2);
    const float2 c45 = *reinterpret_cast<const float2*>(cbase + 4);
    // sample s0   : color (c01.x, c01.y, c23.x)
    // sample s0+1 : color (c23.y, c45.x, c45.y)

    // ---- dists ----
    const float z_next = __shfl_down(zv.x, 1, 64);       // z[s0+2]
    const float dist0 = (zv.y - zv.x) * nrm;
    const float dist1 = (lane == 63) ? (1e10f * nrm) : (z_next - zv.y) * nrm;

    // ---- alpha / survival ----
    const float sig0 = fmaxf(sg.x, 0.0f);
    const float sig1 = fmaxf(sg.y, 0.0f);
    const float e0 = __expf(-sig0 * dist0);
    const float e1 = __expf(-sig1 * dist1);
    const float alpha0 = 1.0f - e0;
    const float alpha1 = 1.0f - e1;
    const float a0 = e0 + 1e-10f;   // (1 - alpha) + 1e-10
    const float a1 = e1 + 1e-10f;

    // ---- exclusive prefix product over 128 samples (2/lane) ----
    float scan = a0 * a1;                 // local pair product
    #pragma unroll
    for (int off = 1; off < 64; off <<= 1) {
        const float n = __shfl_up(scan, off, 64);
        if (lane >= off) scan *= n;
    }
    float excl = __shfl_up(scan, 1, 64);  // product of all pairs before this lane
    if (lane == 0) excl = 1.0f;

    const float T0 = excl;
    const float T1 = excl * a0;
    const float w0 = T0 * alpha0;
    const float w1 = T1 * alpha1;

    // ---- reductions ----
    float acc   = w0 + w1;
    float depth = w0 * zv.x  + w1 * zv.y;
    float cr    = w0 * c01.x + w1 * c23.y;
    float cg    = w0 * c01.y + w1 * c45.x;
    float cb    = w0 * c23.x + w1 * c45.y;
    #pragma unroll
    for (int off = 32; off; off >>= 1) {
        acc   += __shfl_xor(acc,   off, 64);
        depth += __shfl_xor(depth, off, 64);
        cr    += __shfl_xor(cr,    off, 64);
        cg    += __shfl_xor(cg,    off, 64);
        cb    += __shfl_xor(cb,    off, 64);
    }

    // ---- writes ----
    // out layout (flat, f32): rgb[R,3] | weights[R,128] | depth[R] | disp[R] | acc[R]
    const size_t R = N_RAYS;
    float* wout = out + 3 * R + rbase + s0;
    *reinterpret_cast<float2*>(wout) = make_float2(w0, w1);

    if (lane == 0) {
        out[(size_t)ray * 3 + 0] = cr;
        out[(size_t)ray * 3 + 1] = cg;
        out[(size_t)ray * 3 + 2] = cb;
        out[131 * R + ray] = depth;
        out[132 * R + ray] = 1.0f / fmaxf(1e-10f, depth / acc);
        out[133 * R + ray] = acc;
    }
}

extern "C" void kernel_launch(void* const* d_in, const int* in_sizes, int n_in,
                              void* d_out, int out_size, void* d_ws, size_t ws_size,
                              hipStream_t stream) {
    const float* sigma  = (const float*)d_in[0];
    const float* colors = (const float*)d_in[1];
    const float* z_vals = (const float*)d_in[2];
    const float* rays_d = (const float*)d_in[3];
    float* out = (float*)d_out;

    dim3 block(256);                 // 4 waves = 4 rays per block
    dim3 grid(N_RAYS / 4);           // 262144 / 4 = 65536 blocks
    volrend_kernel<<<grid, block, 0, stream>>>(sigma, colors, z_vals, rays_d, out);
}